// Round 7
// baseline (192.920 us; speedup 1.0000x reference)
//
#include <hip/hip_runtime.h>
#include <hip/hip_bf16.h>

#define NN 9216
#define CC 256
#define LOG2E 1.4426950408889634f

typedef __attribute__((ext_vector_type(8))) short short8;
typedef __attribute__((ext_vector_type(16))) float floatx16;
typedef __attribute__((ext_vector_type(4))) float floatx4;
typedef __attribute__((ext_vector_type(4))) unsigned short ushortx4;

#if __has_builtin(__builtin_amdgcn_exp2f)
#define fexp2 __builtin_amdgcn_exp2f
#else
#define fexp2 exp2f
#endif

__device__ __forceinline__ unsigned short f2bf(float f) {
    unsigned u = __float_as_uint(f);
    u = u + 0x7fffu + ((u >> 16) & 1u);
    return (unsigned short)(u >> 16);
}
__device__ __forceinline__ float bf2f(unsigned short s) {
    return __uint_as_float(((unsigned)s) << 16);
}
__device__ __forceinline__ unsigned pack2bf(float a, float b) {
    union { __hip_bfloat162 h; unsigned u; } cv;
    cv.h = __float22bfloat162_rn(make_float2(a, b));
    return cv.u;
}
__device__ __forceinline__ floatx16 mfma_bf16(short8 a, short8 b, floatx16 c) {
    return __builtin_amdgcn_mfma_f32_32x32x16_bf16(a, b, c, 0, 0, 0);
}
// async global->LDS, 16B per lane; lds dest is wave-uniform base (HW adds lane*16)
__device__ __forceinline__ void gload16(void* l, const void* g) {
    __builtin_amdgcn_global_load_lds(
        (const __attribute__((address_space(1))) unsigned int*)g,
        (__attribute__((address_space(3))) unsigned int*)l, 16, 0, 0);
}

// K0: transpose+hi/lo-split inputs into B-fragment order XB/EB[nt][kb][lane][8].
__global__ __launch_bounds__(256) void prep(
    const float* __restrict__ x, const float* __restrict__ xe,
    short* __restrict__ XBhi, short* __restrict__ XBlo,
    short* __restrict__ EBhi, short* __restrict__ EBlo)
{
    int t = threadIdx.x;
    const float* in = blockIdx.y ? xe : x;
    short* Dhi = blockIdx.y ? EBhi : XBhi;
    short* Dlo = blockIdx.y ? EBlo : XBlo;
    int tl = t & 31, sub = t >> 5;
    int nt = blockIdx.x >> 2, q4 = blockIdx.x & 3;
    int sub2 = q4 * 8 + sub;            // 0..31
    int kb_ = sub2 >> 1, hl = sub2 & 1;
    int n = nt * 32 + tl;
    int c0 = kb_ * 16 + hl * 8;
    union { unsigned short us[8]; short8 v8; } hi, lo;
#pragma unroll
    for (int j = 0; j < 8; ++j) {
        float val = in[(size_t)(c0 + j) * NN + n];
        unsigned short hb = f2bf(val);
        hi.us[j] = hb;
        lo.us[j] = f2bf(val - bf2f(hb));
    }
    size_t off = (((size_t)nt * 16 + kb_) * 64 + hl * 32 + tl) * 8;
    *(short8*)(Dhi + off) = hi.v8;
    *(short8*)(Dlo + off) = lo.v8;
}

// K0b: weights -> A-fragment order WA[ot][kb][lane][8], hi/lo split.
__global__ __launch_bounds__(256) void wprep(
    const float* __restrict__ qw, const float* __restrict__ kw,
    const float* __restrict__ vw,
    short* __restrict__ WAhi, short* __restrict__ WAlo)
{
    int g = blockIdx.x * 256 + threadIdx.x;     // 0..10239
    int lane = g & 63, kb_ = (g >> 6) & 15, ot = g >> 10;
    int o = lane & 31, half = lane >> 5;
    int c0 = kb_ * 16 + half * 8;
    const float* wsrc;
    int orow;
    float scale = 1.f;
    if (ot == 0) { wsrc = qw; orow = o; scale = LOG2E; }
    else if (ot == 1) { wsrc = kw; orow = o; }
    else { wsrc = vw; orow = (ot - 2) * 32 + o; }
    union { unsigned short us[8]; short8 v8; } hi, lo;
#pragma unroll
    for (int j = 0; j < 8; ++j) {
        float val = wsrc[(size_t)orow * 256 + c0 + j] * scale;
        unsigned short hb = f2bf(val);
        hi.us[j] = hb;
        lo.us[j] = f2bf(val - bf2f(hb));
    }
    size_t off = (((size_t)ot * 16 + kb_) * 64 + lane) * 8;
    *(short8*)(WAhi + off) = hi.v8;
    *(short8*)(WAlo + off) = lo.v8;
}

// K1: all projections via MFMA (see round-2 notes). grid (144, 5), 256 thr.
__global__ __launch_bounds__(256) void gemm_all(
    const short* __restrict__ XBhi, const short* __restrict__ XBlo,
    const short* __restrict__ EBhi, const short* __restrict__ EBlo,
    const short* __restrict__ WAhi, const short* __restrict__ WAlo,
    const float* __restrict__ qb, const float* __restrict__ kb,
    const float* __restrict__ hpos, const float* __restrict__ wpos,
    const float* __restrict__ vb,
    short* __restrict__ Qhi, short* __restrict__ Qlo,
    short* __restrict__ KP2, short* __restrict__ VF)
{
    __shared__ float lds[4][1024];
    int t = threadIdx.x;
    int wv = t >> 6, lane = t & 63, ln = lane & 31, h = lane >> 5;
    int nt = blockIdx.x * 2 + (wv & 1);
    int tile = blockIdx.y * 2 + (wv >> 1);

    const short* Bhi = (tile == 0 ? XBhi : EBhi) + (size_t)nt * 8192 + lane * 8;
    const short* Blo = (tile == 0 ? XBlo : EBlo) + (size_t)nt * 8192 + lane * 8;
    const short* Ahi = WAhi + (size_t)tile * 8192 + lane * 8;
    const short* Alo = WAlo + (size_t)tile * 8192 + lane * 8;

    floatx16 D;
#pragma unroll
    for (int r = 0; r < 16; ++r) D[r] = 0.f;
#pragma unroll
    for (int k = 0; k < 16; ++k) {
        short8 bh = *(const short8*)(Bhi + k * 512);
        short8 bl = *(const short8*)(Blo + k * 512);
        short8 ah = *(const short8*)(Ahi + k * 512);
        short8 al = *(const short8*)(Alo + k * 512);
        D = mfma_bf16(ah, bh, D);
        D = mfma_bf16(ah, bl, D);
        D = mfma_bf16(al, bh, D);
    }

    float* L = lds[wv];
#pragma unroll
    for (int r = 0; r < 16; ++r) {
        int row = (r & 3) + 8 * (r >> 2) + 4 * h;
        L[row * 32 + ((ln + row) & 31)] = D[r];     // (col+row)&31 bank swizzle
    }
    __syncthreads();

    if (tile == 0) {
        int n = nt * 32 + ln;
#pragma unroll
        for (int it = 0; it < 2; ++it) {
            int j0 = it * 16 + h * 8;
            union { unsigned short us[8]; short8 v8; } qh_, ql_;
#pragma unroll
            for (int jj = 0; jj < 8; ++jj) {
                int row = j0 + jj;
                float d = L[row * 32 + ((ln + row) & 31)] + qb[row] * LOG2E;
                unsigned short hb = f2bf(d);
                qh_.us[jj] = hb;
                ql_.us[jj] = f2bf(d - bf2f(hb));
            }
            *(short8*)(Qhi + (size_t)n * 32 + j0) = qh_.v8;
            *(short8*)(Qlo + (size_t)n * 32 + j0) = ql_.v8;
        }
    } else if (tile == 1) {
        int n = nt * 32 + ln;
        int hh = ((n >> 5) * 683) >> 11;     // n/96
        int ww = n - hh * 96;
#pragma unroll
        for (int it = 0; it < 2; ++it) {
            int jb0 = it * 16 + h * 8;
            union { unsigned short us[8]; short8 v8; } o;
#pragma unroll
            for (int jj = 0; jj < 8; ++jj) {
                int row = jb0 + jj;
                float d = L[row * 32 + ((ln + row) & 31)]
                        + kb[row] + hpos[row * 96 + hh] + wpos[row * 96 + ww];
                o.us[jj] = f2bf(d);
            }
            *(short8*)(KP2 + (size_t)nt * 1024 + it * 512 + h * 256 + ln * 8) = o.v8;
        }
    } else {
        int cc = tile - 2;
        float bias = vb[cc * 32 + ln];
#pragma unroll
        for (int it = 0; it < 2; ++it) {
            union { unsigned short us[8]; short8 v8; } o;
#pragma unroll
            for (int ee = 0; ee < 8; ++ee) {
                int ml = it * 16 + h * 8 + ee;
                float d = L[ln * 32 + ((ml + ln) & 31)];
                o.us[ee] = f2bf(d + bias);
            }
            *(short8*)(VF + ((size_t)(nt * 2 + it) * 8 + cc) * 512 + lane * 8) = o.v8;
        }
    }
}

// K3: flash attention, LDS-staged V/KP with double-buffered global_load_lds.
// Block = 128 thr = 2 waves; wave = 64 n x 128 c (c-half = wave id); block covers
// 64 n x 256 c of output for one m-quarter. Per 32-m chunk: stage V (16KB) + KP
// (2KB) into LDS ONCE (9 gload16/wave), issued BEFORE the current chunk's compute
// and drained at the end-of-iter __syncthreads -> loads hide under compute.
// Each staged V byte is ds_read once (wave reads only its c-half); each V frag
// feeds 2 PV MFMAs (two n-tiles). Chip V traffic from L2: 1.33 GB -> 680 MB, and
// it moves at LDS rate instead of the per-wave VMEM path (the round-3..6 wall).
// QK/softmax x2 redundant across c-halves (cheap). Fixed-max softmax (max=0).
// grid = 144 ntb(64n) * 4 mq = 576 blocks.
#define STAGE(B, SP) do {                                                          \
    const char* vs_ = Vg + (size_t)(SP) * 16384 + wv * 8192 + lane * 16;           \
    char* vd_ = (char*)(&sbuf[(B)][0]) + wv * 8192;                                \
    gload16(vd_,        vs_);                                                      \
    gload16(vd_ + 1024, vs_ + 1024);                                               \
    gload16(vd_ + 2048, vs_ + 2048);                                               \
    gload16(vd_ + 3072, vs_ + 3072);                                               \
    gload16(vd_ + 4096, vs_ + 4096);                                               \
    gload16(vd_ + 5120, vs_ + 5120);                                               \
    gload16(vd_ + 6144, vs_ + 6144);                                               \
    gload16(vd_ + 7168, vs_ + 7168);                                               \
    gload16((char*)(&sbuf[(B)][8192]) + wv * 1024,                                 \
            Kg + (size_t)(SP) * 2048 + wv * 1024 + lane * 16);                     \
} while (0)

// one n-tile: QK (hi/lo) -> exp2 softmax -> pack -> PV into 4 c-tile accumulators
#define NTSTEP(QH0, QL0, QH1, QL1, OA, OB, OC, OD, LACC) do {                      \
    floatx16 S = {0.f,0.f,0.f,0.f,0.f,0.f,0.f,0.f,0.f,0.f,0.f,0.f,0.f,0.f,0.f,0.f}; \
    S = mfma_bf16(ah0, QH0, S);                                                    \
    S = mfma_bf16(ah0, QL0, S);                                                    \
    S = mfma_bf16(ah1, QH1, S);                                                    \
    S = mfma_bf16(ah1, QL1, S);                                                    \
    float ps = 0.f;                                                                \
    _Pragma("unroll") for (int r = 0; r < 16; ++r) { S[r] = fexp2(S[r]); ps += S[r]; } \
    ps += __shfl_xor(ps, 32); LACC += ps;                                          \
    unsigned w0 = pack2bf(S[0], S[1]),  w1 = pack2bf(S[2], S[3]);                  \
    unsigned w2 = pack2bf(S[4], S[5]),  w3 = pack2bf(S[6], S[7]);                  \
    unsigned w4 = pack2bf(S[8], S[9]),  w5 = pack2bf(S[10], S[11]);                \
    unsigned w6 = pack2bf(S[12], S[13]), w7 = pack2bf(S[14], S[15]);               \
    {   unsigned p0 = h ? w0 : w2, p1 = h ? w1 : w3;                               \
        unsigned e0 = (unsigned)__shfl_xor((int)p0, 32);                           \
        unsigned e1 = (unsigned)__shfl_xor((int)p1, 32);                           \
        union { unsigned u[4]; short8 v; } pf;                                     \
        pf.u[0] = h ? e0 : w0; pf.u[1] = h ? e1 : w1;                              \
        pf.u[2] = h ? w2 : e0; pf.u[3] = h ? w3 : e1;                              \
        OA = mfma_bf16(v00, pf.v, OA); OB = mfma_bf16(v01, pf.v, OB);              \
        OC = mfma_bf16(v02, pf.v, OC); OD = mfma_bf16(v03, pf.v, OD); }            \
    {   unsigned p0 = h ? w4 : w6, p1 = h ? w5 : w7;                               \
        unsigned e0 = (unsigned)__shfl_xor((int)p0, 32);                           \
        unsigned e1 = (unsigned)__shfl_xor((int)p1, 32);                           \
        union { unsigned u[4]; short8 v; } pf;                                     \
        pf.u[0] = h ? e0 : w4; pf.u[1] = h ? e1 : w5;                              \
        pf.u[2] = h ? w6 : e0; pf.u[3] = h ? w7 : e1;                              \
        OA = mfma_bf16(v10, pf.v, OA); OB = mfma_bf16(v11, pf.v, OB);              \
        OC = mfma_bf16(v12, pf.v, OC); OD = mfma_bf16(v13, pf.v, OD); }            \
} while (0)

#define OGW(CF, NT, OG) { _Pragma("unroll") for (int r = 0; r < 16; ++r) {         \
    int row = wv * 128 + (CF) * 32 + (r & 3) + 8 * (r >> 2) + 4 * h;               \
    Opart[obase + (size_t)row * NN + n0 + (NT) * 32 + ln] = f2bf(OG[r]); } }

__global__ __launch_bounds__(128) void flash(
    const short* __restrict__ Qhi, const short* __restrict__ Qlo,
    const short* __restrict__ KP2, const short* __restrict__ VF,
    unsigned short* __restrict__ Opart, float* __restrict__ Lpart)
{
    __shared__ short sbuf[2][9216];   // per buf: [0,16KB)=V chunk 32m x 256c, [16KB,18KB)=KP
    int t = threadIdx.x;
    int wv = t >> 6;                  // c-half
    int lane = t & 63;
    int ln = lane & 31;
    int h = lane >> 5;
    int bx = blockIdx.x;
    int ntb = bx >> 2, mq = bx & 3;
    int n0 = ntb * 64;
    int mstart = mq * 2304;

    int qoffA = (n0 + ln) * 32 + h * 8;
    int qoffB = qoffA + 32 * 32;
    short8 qAh0 = *(const short8*)(Qhi + qoffA);
    short8 qAl0 = *(const short8*)(Qlo + qoffA);
    short8 qAh1 = *(const short8*)(Qhi + qoffA + 16);
    short8 qAl1 = *(const short8*)(Qlo + qoffA + 16);
    short8 qBh0 = *(const short8*)(Qhi + qoffB);
    short8 qBl0 = *(const short8*)(Qlo + qoffB);
    short8 qBh1 = *(const short8*)(Qhi + qoffB + 16);
    short8 qBl1 = *(const short8*)(Qlo + qoffB + 16);

    const char* Vg = (const char*)VF + (size_t)(mstart >> 4) * 8192;   // 8KB per 16-m
    const char* Kg = (const char*)KP2 + (size_t)(mstart >> 5) * 2048;  // 2KB per 32-m

    floatx16 OA0, OA1, OA2, OA3, OB0, OB1, OB2, OB3;
#pragma unroll
    for (int r = 0; r < 16; ++r) {
        OA0[r] = 0.f; OA1[r] = 0.f; OA2[r] = 0.f; OA3[r] = 0.f;
        OB0[r] = 0.f; OB1[r] = 0.f; OB2[r] = 0.f; OB3[r] = 0.f;
    }
    float lA = 0.f, lB = 0.f;

    int cur = 0;
    STAGE(0, 0);
    __syncthreads();                  // drains vmcnt(0): chunk 0 resident

    for (int sp = 0; sp < 72; ++sp) {
        if (sp < 71) STAGE(cur ^ 1, sp + 1);   // fly under this chunk's compute

        const short* vbase = &sbuf[cur][0] + wv * 2048;   // this wave's c-half
        const short* kbase = &sbuf[cur][8192];
        short8 ah0 = *(const short8*)(kbase + lane * 8);
        short8 ah1 = *(const short8*)(kbase + 512 + lane * 8);
        short8 v00 = *(const short8*)(vbase + lane * 8);
        short8 v01 = *(const short8*)(vbase + 512 + lane * 8);
        short8 v02 = *(const short8*)(vbase + 1024 + lane * 8);
        short8 v03 = *(const short8*)(vbase + 1536 + lane * 8);
        short8 v10 = *(const short8*)(vbase + 4096 + lane * 8);
        short8 v11 = *(const short8*)(vbase + 4608 + lane * 8);
        short8 v12 = *(const short8*)(vbase + 5120 + lane * 8);
        short8 v13 = *(const short8*)(vbase + 5632 + lane * 8);

        NTSTEP(qAh0, qAl0, qAh1, qAl1, OA0, OA1, OA2, OA3, lA);
        NTSTEP(qBh0, qBl0, qBh1, qBl1, OB0, OB1, OB2, OB3, lB);

        __syncthreads();              // stage complete + all reads of buf[cur] done
        cur ^= 1;
    }

    if (wv == 0 && lane < 32) {
        Lpart[mq * NN + n0 + ln] = lA;
        Lpart[mq * NN + n0 + 32 + ln] = lB;
    }
    size_t obase = (size_t)mq * ((size_t)CC * NN);
    OGW(0, 0, OA0) OGW(1, 0, OA1) OGW(2, 0, OA2) OGW(3, 0, OA3)
    OGW(0, 1, OB0) OGW(1, 1, OB1) OGW(2, 1, OB2) OGW(3, 1, OB3)
}

// K4: fixed-max parts => single weight W[n] = gamma / sum_q L_q[n]. grid 36x256.
__global__ __launch_bounds__(256) void stats(
    const float* __restrict__ Lpart, const float* __restrict__ gamma,
    float* __restrict__ W)
{
    int n = blockIdx.x * 256 + threadIdx.x;
    float L = Lpart[n] + Lpart[NN + n] + Lpart[2 * NN + n] + Lpart[3 * NN + n];
    W[n] = gamma[0] / L;
}

// K5: out[c][n] = (sum_q Opart_q[c][n]) * W[n] + x[c][n]
__global__ __launch_bounds__(256) void combine(
    const unsigned short* __restrict__ Opart, const float* __restrict__ W,
    const float* __restrict__ x, float* __restrict__ out)
{
    int i = blockIdx.x * 256 + threadIdx.x;   // float4 index
    int flat = i * 4;
    int n = flat % NN;                        // 4-aligned, NN%4==0 so no row cross
    floatx4 acc = *(const floatx4*)&x[flat];
    floatx4 w = *(const floatx4*)&W[n];
    float s0 = 0.f, s1 = 0.f, s2 = 0.f, s3 = 0.f;
#pragma unroll
    for (int q = 0; q < 4; ++q) {
        ushortx4 o = *(const ushortx4*)(Opart + (size_t)q * ((size_t)CC * NN) + flat);
        s0 += bf2f(o[0]); s1 += bf2f(o[1]); s2 += bf2f(o[2]); s3 += bf2f(o[3]);
    }
    acc[0] += s0 * w[0]; acc[1] += s1 * w[1]; acc[2] += s2 * w[2]; acc[3] += s3 * w[3];
    *(floatx4*)&out[flat] = acc;
}

extern "C" void kernel_launch(void* const* d_in, const int* in_sizes, int n_in,
                              void* d_out, int out_size, void* d_ws, size_t ws_size,
                              hipStream_t stream) {
    const float* x  = (const float*)d_in[0];
    const float* xe = (const float*)d_in[1];
    const float* qw = (const float*)d_in[2];
    const float* qb = (const float*)d_in[3];
    const float* kw = (const float*)d_in[4];
    const float* kb = (const float*)d_in[5];
    const float* vw = (const float*)d_in[6];
    const float* vb = (const float*)d_in[7];
    const float* hp = (const float*)d_in[8];
    const float* wp = (const float*)d_in[9];
    const float* gm = (const float*)d_in[10];

    char* ws = (char*)d_ws;
    short* Qhi  = (short*)(ws + 0);                 // 589824 B
    short* Qlo  = (short*)(ws + 589824);            // 589824 B
    short* KP2  = (short*)(ws + 1179648);           // 589824 B
    short* WAhi = (short*)(ws + 1769472);           // 163840 B
    short* WAlo = (short*)(ws + 1933312);           // 163840 B
    short* VF   = (short*)(ws + 2097152);           // 4718592 B, ends 6815744
    unsigned short* Opart = (unsigned short*)(ws + 6815744);   // 18874368 B, ends 25690112
    // XB/EB staging overlays Opart (consumed by gemm_all before flash writes Opart)
    short* XBhi = (short*)(ws + 6815744);           // 4718592 B each
    short* XBlo = (short*)(ws + 11534336);
    short* EBhi = (short*)(ws + 16252928);
    short* EBlo = (short*)(ws + 20971520);
    float* Lpart = (float*)(ws + 25837568);         // 147456 B
    float* W     = (float*)(ws + 25985024);         // 36864 B used

    prep<<<dim3(1152, 2), dim3(256), 0, stream>>>(x, xe, XBhi, XBlo, EBhi, EBlo);
    wprep<<<dim3(40), dim3(256), 0, stream>>>(qw, kw, vw, WAhi, WAlo);
    gemm_all<<<dim3(144, 5), dim3(256), 0, stream>>>(
        XBhi, XBlo, EBhi, EBlo, WAhi, WAlo, qb, kb, hp, wp, vb, Qhi, Qlo, KP2, VF);
    flash<<<dim3(576), dim3(128), 0, stream>>>(Qhi, Qlo, KP2, VF, Opart, Lpart);
    stats<<<dim3(36), dim3(256), 0, stream>>>(Lpart, gm, W);
    combine<<<dim3(2304), dim3(256), 0, stream>>>(Opart, W, x, (float*)d_out);
}

// Round 8
// 137.808 us; speedup vs baseline: 1.3999x; 1.3999x over previous
//
#include <hip/hip_runtime.h>
#include <hip/hip_bf16.h>

#define NN 9216
#define CC 256
#define LOG2E 1.4426950408889634f

typedef __attribute__((ext_vector_type(8))) short short8;
typedef __attribute__((ext_vector_type(16))) float floatx16;
typedef __attribute__((ext_vector_type(4))) float floatx4;
typedef __attribute__((ext_vector_type(4))) unsigned short ushortx4;

#if __has_builtin(__builtin_amdgcn_exp2f)
#define fexp2 __builtin_amdgcn_exp2f
#else
#define fexp2 exp2f
#endif

__device__ __forceinline__ unsigned short f2bf(float f) {
    unsigned u = __float_as_uint(f);
    u = u + 0x7fffu + ((u >> 16) & 1u);
    return (unsigned short)(u >> 16);
}
__device__ __forceinline__ float bf2f(unsigned short s) {
    return __uint_as_float(((unsigned)s) << 16);
}
__device__ __forceinline__ unsigned pack2bf(float a, float b) {
    union { __hip_bfloat162 h; unsigned u; } cv;
    cv.h = __float22bfloat162_rn(make_float2(a, b));
    return cv.u;
}
__device__ __forceinline__ floatx16 mfma_bf16(short8 a, short8 b, floatx16 c) {
    return __builtin_amdgcn_mfma_f32_32x32x16_bf16(a, b, c, 0, 0, 0);
}

// K0: transpose+hi/lo-split inputs into B-fragment order XB/EB[nt][kb][lane][8].
__global__ __launch_bounds__(256) void prep(
    const float* __restrict__ x, const float* __restrict__ xe,
    short* __restrict__ XBhi, short* __restrict__ XBlo,
    short* __restrict__ EBhi, short* __restrict__ EBlo)
{
    int t = threadIdx.x;
    const float* in = blockIdx.y ? xe : x;
    short* Dhi = blockIdx.y ? EBhi : XBhi;
    short* Dlo = blockIdx.y ? EBlo : XBlo;
    int tl = t & 31, sub = t >> 5;
    int nt = blockIdx.x >> 2, q4 = blockIdx.x & 3;
    int sub2 = q4 * 8 + sub;            // 0..31
    int kb_ = sub2 >> 1, hl = sub2 & 1;
    int n = nt * 32 + tl;
    int c0 = kb_ * 16 + hl * 8;
    union { unsigned short us[8]; short8 v8; } hi, lo;
#pragma unroll
    for (int j = 0; j < 8; ++j) {
        float val = in[(size_t)(c0 + j) * NN + n];
        unsigned short hb = f2bf(val);
        hi.us[j] = hb;
        lo.us[j] = f2bf(val - bf2f(hb));
    }
    size_t off = (((size_t)nt * 16 + kb_) * 64 + hl * 32 + tl) * 8;
    *(short8*)(Dhi + off) = hi.v8;
    *(short8*)(Dlo + off) = lo.v8;
}

// K0b: weights -> A-fragment order WA[ot][kb][lane][8], hi/lo split.
__global__ __launch_bounds__(256) void wprep(
    const float* __restrict__ qw, const float* __restrict__ kw,
    const float* __restrict__ vw,
    short* __restrict__ WAhi, short* __restrict__ WAlo)
{
    int g = blockIdx.x * 256 + threadIdx.x;     // 0..10239
    int lane = g & 63, kb_ = (g >> 6) & 15, ot = g >> 10;
    int o = lane & 31, half = lane >> 5;
    int c0 = kb_ * 16 + half * 8;
    const float* wsrc;
    int orow;
    float scale = 1.f;
    if (ot == 0) { wsrc = qw; orow = o; scale = LOG2E; }
    else if (ot == 1) { wsrc = kw; orow = o; }
    else { wsrc = vw; orow = (ot - 2) * 32 + o; }
    union { unsigned short us[8]; short8 v8; } hi, lo;
#pragma unroll
    for (int j = 0; j < 8; ++j) {
        float val = wsrc[(size_t)orow * 256 + c0 + j] * scale;
        unsigned short hb = f2bf(val);
        hi.us[j] = hb;
        lo.us[j] = f2bf(val - bf2f(hb));
    }
    size_t off = (((size_t)ot * 16 + kb_) * 64 + lane) * 8;
    *(short8*)(WAhi + off) = hi.v8;
    *(short8*)(WAlo + off) = lo.v8;
}

// K1: all projections via MFMA (see round-2 notes). grid (144, 5), 256 thr.
__global__ __launch_bounds__(256) void gemm_all(
    const short* __restrict__ XBhi, const short* __restrict__ XBlo,
    const short* __restrict__ EBhi, const short* __restrict__ EBlo,
    const short* __restrict__ WAhi, const short* __restrict__ WAlo,
    const float* __restrict__ qb, const float* __restrict__ kb,
    const float* __restrict__ hpos, const float* __restrict__ wpos,
    const float* __restrict__ vb,
    short* __restrict__ Qhi, short* __restrict__ Qlo,
    short* __restrict__ KP2, short* __restrict__ VF)
{
    __shared__ float lds[4][1024];
    int t = threadIdx.x;
    int wv = t >> 6, lane = t & 63, ln = lane & 31, h = lane >> 5;
    int nt = blockIdx.x * 2 + (wv & 1);
    int tile = blockIdx.y * 2 + (wv >> 1);

    const short* Bhi = (tile == 0 ? XBhi : EBhi) + (size_t)nt * 8192 + lane * 8;
    const short* Blo = (tile == 0 ? XBlo : EBlo) + (size_t)nt * 8192 + lane * 8;
    const short* Ahi = WAhi + (size_t)tile * 8192 + lane * 8;
    const short* Alo = WAlo + (size_t)tile * 8192 + lane * 8;

    floatx16 D;
#pragma unroll
    for (int r = 0; r < 16; ++r) D[r] = 0.f;
#pragma unroll
    for (int k = 0; k < 16; ++k) {
        short8 bh = *(const short8*)(Bhi + k * 512);
        short8 bl = *(const short8*)(Blo + k * 512);
        short8 ah = *(const short8*)(Ahi + k * 512);
        short8 al = *(const short8*)(Alo + k * 512);
        D = mfma_bf16(ah, bh, D);
        D = mfma_bf16(ah, bl, D);
        D = mfma_bf16(al, bh, D);
    }

    float* L = lds[wv];
#pragma unroll
    for (int r = 0; r < 16; ++r) {
        int row = (r & 3) + 8 * (r >> 2) + 4 * h;
        L[row * 32 + ((ln + row) & 31)] = D[r];     // (col+row)&31 bank swizzle
    }
    __syncthreads();

    if (tile == 0) {
        int n = nt * 32 + ln;
#pragma unroll
        for (int it = 0; it < 2; ++it) {
            int j0 = it * 16 + h * 8;
            union { unsigned short us[8]; short8 v8; } qh_, ql_;
#pragma unroll
            for (int jj = 0; jj < 8; ++jj) {
                int row = j0 + jj;
                float d = L[row * 32 + ((ln + row) & 31)] + qb[row] * LOG2E;
                unsigned short hb = f2bf(d);
                qh_.us[jj] = hb;
                ql_.us[jj] = f2bf(d - bf2f(hb));
            }
            *(short8*)(Qhi + (size_t)n * 32 + j0) = qh_.v8;
            *(short8*)(Qlo + (size_t)n * 32 + j0) = ql_.v8;
        }
    } else if (tile == 1) {
        int n = nt * 32 + ln;
        int hh = ((n >> 5) * 683) >> 11;     // n/96
        int ww = n - hh * 96;
#pragma unroll
        for (int it = 0; it < 2; ++it) {
            int jb0 = it * 16 + h * 8;
            union { unsigned short us[8]; short8 v8; } o;
#pragma unroll
            for (int jj = 0; jj < 8; ++jj) {
                int row = jb0 + jj;
                float d = L[row * 32 + ((ln + row) & 31)]
                        + kb[row] + hpos[row * 96 + hh] + wpos[row * 96 + ww];
                o.us[jj] = f2bf(d);
            }
            *(short8*)(KP2 + (size_t)nt * 1024 + it * 512 + h * 256 + ln * 8) = o.v8;
        }
    } else {
        int cc = tile - 2;
        float bias = vb[cc * 32 + ln];
#pragma unroll
        for (int it = 0; it < 2; ++it) {
            union { unsigned short us[8]; short8 v8; } o;
#pragma unroll
            for (int ee = 0; ee < 8; ++ee) {
                int ml = it * 16 + h * 8 + ee;
                float d = L[ln * 32 + ((ml + ln) & 31)];
                o.us[ee] = f2bf(d + bias);
            }
            *(short8*)(VF + ((size_t)(nt * 2 + it) * 8 + cc) * 512 + lane * 8) = o.v8;
        }
    }
}

// K3: flash attention, m-split 2-wave blocks. Wave = 32 n x 256 c x 1152 m
// (S computed once chip-wide; no c-redundancy). Block = 2 m-halves of one
// (nt, mq); O combined via ONE 32KB LDS exchange + single barrier, both waves
// store half the c-rows. Grid = 288 nt x 4 mq = 1152 blocks = 2304 waves
// (~9/CU, saturating the 2-waves/SIMD 256-reg cap; vs 1.1/SIMD in rounds 3-6).
// XCD-bijective swizzle pins each mq-part to an XCD pair -> that XCD's L2
// holds its V-part (1.18MB) + Q + KP (~3MB < 4MB) -> V loads are L2 hits.
// s_setprio(1) around the PV MFMA cluster (T5: barrier-free independent waves).
// Fixed-max softmax (max=0): energies ~N(0,~10) in log2 domain, exact in f32.
#define FSTEP(AH0, AH1, M0) do {                                                      \
    const size_t mo_ = (size_t)(M0) * 256;                                            \
    short8 va0 = *(const short8*)(Vb + mo_);                                          \
    short8 va1 = *(const short8*)(Vb + mo_ + 512);                                    \
    short8 va2 = *(const short8*)(Vb + mo_ + 1024);                                   \
    short8 va3 = *(const short8*)(Vb + mo_ + 1536);                                   \
    floatx16 S = {0.f,0.f,0.f,0.f,0.f,0.f,0.f,0.f,0.f,0.f,0.f,0.f,0.f,0.f,0.f,0.f};  \
    S = mfma_bf16(AH0, qf00, S);                                                      \
    S = mfma_bf16(AH0, qf01, S);                                                      \
    S = mfma_bf16(AH1, qf10, S);                                                      \
    S = mfma_bf16(AH1, qf11, S);                                                      \
    short8 va4 = *(const short8*)(Vb + mo_ + 2048);                                   \
    short8 va5 = *(const short8*)(Vb + mo_ + 2560);                                   \
    short8 va6 = *(const short8*)(Vb + mo_ + 3072);                                   \
    short8 va7 = *(const short8*)(Vb + mo_ + 3584);                                   \
    float ps = 0.f;                                                                   \
    _Pragma("unroll") for (int r = 0; r < 16; ++r) { S[r] = fexp2(S[r]); ps += S[r]; } \
    ps += __shfl_xor(ps, 32); l_run += ps;                                            \
    unsigned w0 = pack2bf(S[0], S[1]),  w1 = pack2bf(S[2], S[3]);                     \
    unsigned w2 = pack2bf(S[4], S[5]),  w3 = pack2bf(S[6], S[7]);                     \
    unsigned w4 = pack2bf(S[8], S[9]),  w5 = pack2bf(S[10], S[11]);                   \
    unsigned w6 = pack2bf(S[12], S[13]), w7 = pack2bf(S[14], S[15]);                  \
    __builtin_amdgcn_s_setprio(1);                                                    \
    {   unsigned p0 = h ? w0 : w2, p1 = h ? w1 : w3;                                  \
        unsigned e0 = (unsigned)__shfl_xor((int)p0, 32);                              \
        unsigned e1 = (unsigned)__shfl_xor((int)p1, 32);                              \
        union { unsigned u[4]; short8 v; } pf;                                        \
        pf.u[0] = h ? e0 : w0; pf.u[1] = h ? e1 : w1;                                 \
        pf.u[2] = h ? w2 : e0; pf.u[3] = h ? w3 : e1;                                 \
        O0 = mfma_bf16(va0, pf.v, O0); O1 = mfma_bf16(va1, pf.v, O1);                 \
        O2 = mfma_bf16(va2, pf.v, O2); O3 = mfma_bf16(va3, pf.v, O3);                 \
        O4 = mfma_bf16(va4, pf.v, O4); O5 = mfma_bf16(va5, pf.v, O5);                 \
        O6 = mfma_bf16(va6, pf.v, O6); O7 = mfma_bf16(va7, pf.v, O7); }               \
    short8 vb0 = *(const short8*)(Vb + mo_ + 4096);                                   \
    short8 vb1 = *(const short8*)(Vb + mo_ + 4608);                                   \
    short8 vb2 = *(const short8*)(Vb + mo_ + 5120);                                   \
    short8 vb3 = *(const short8*)(Vb + mo_ + 5632);                                   \
    short8 vb4 = *(const short8*)(Vb + mo_ + 6144);                                   \
    short8 vb5 = *(const short8*)(Vb + mo_ + 6656);                                   \
    short8 vb6 = *(const short8*)(Vb + mo_ + 7168);                                   \
    short8 vb7 = *(const short8*)(Vb + mo_ + 7680);                                   \
    {   unsigned p0 = h ? w4 : w6, p1 = h ? w5 : w7;                                  \
        unsigned e0 = (unsigned)__shfl_xor((int)p0, 32);                              \
        unsigned e1 = (unsigned)__shfl_xor((int)p1, 32);                              \
        union { unsigned u[4]; short8 v; } pf;                                        \
        pf.u[0] = h ? e0 : w4; pf.u[1] = h ? e1 : w5;                                 \
        pf.u[2] = h ? w6 : e0; pf.u[3] = h ? w7 : e1;                                 \
        O0 = mfma_bf16(vb0, pf.v, O0); O1 = mfma_bf16(vb1, pf.v, O1);                 \
        O2 = mfma_bf16(vb2, pf.v, O2); O3 = mfma_bf16(vb3, pf.v, O3);                 \
        O4 = mfma_bf16(vb4, pf.v, O4); O5 = mfma_bf16(vb5, pf.v, O5);                 \
        O6 = mfma_bf16(vb6, pf.v, O6); O7 = mfma_bf16(vb7, pf.v, O7); }               \
    __builtin_amdgcn_s_setprio(0);                                                    \
} while (0)

#define OSHW(SL, OG) { _Pragma("unroll") for (int r = 0; r < 16; ++r) \
    Osh[((SL) * 16 + r) * 64 + lane] = OG[r]; }
#define OSTORE(G, OG) { _Pragma("unroll") for (int r = 0; r < 16; ++r) {   \
    float v_ = OG[r] + Osh[((G) * 16 + r) * 64 + lane];                    \
    int row = (G) * 32 + (r & 3) + 8 * (r >> 2) + 4 * h;                   \
    Opart[obase + (size_t)row * NN + n0 + ln] = f2bf(v_); } }

__global__ __launch_bounds__(128, 2) void flash(
    const short* __restrict__ Qhi, const short* __restrict__ Qlo,
    const short* __restrict__ KP2, const short* __restrict__ VF,
    unsigned short* __restrict__ Opart, float* __restrict__ Lpart)
{
    __shared__ float Osh[8192];       // 32 KB cross-wave O exchange
    __shared__ float Lsh[2][32];

    int t = threadIdx.x;
    int wv = t >> 6;                  // m-half within block
    int lane = t & 63;
    int ln = lane & 31;
    int h = lane >> 5;
    // XCD-bijective swizzle: consecutive blockIdx round-robin XCDs; give each
    // mq-part a dedicated XCD pair so its V-part stays L2-resident.
    int g = blockIdx.x;
    int xc = g & 7;
    int mq = xc >> 1;
    int nt = (g >> 3) * 2 + (xc & 1);   // 0..287, bijective
    int n0 = nt * 32;
    int mw = mq * 2304 + wv * 1152;     // this wave's m-subrange (36 chunks of 32)

    int qoff = (n0 + ln) * 32 + h * 8;
    short8 qf00 = *(const short8*)(Qhi + qoff);
    short8 qf01 = *(const short8*)(Qlo + qoff);
    short8 qf10 = *(const short8*)(Qhi + qoff + 16);
    short8 qf11 = *(const short8*)(Qlo + qoff + 16);

    const short* Vb  = VF + (size_t)mw * 256 + (size_t)lane * 8;
    const short* KPb = KP2 + (size_t)mw * 32 + (size_t)lane * 8;

    floatx16 O0, O1, O2, O3, O4, O5, O6, O7;
#pragma unroll
    for (int r = 0; r < 16; ++r) {
        O0[r] = 0.f; O1[r] = 0.f; O2[r] = 0.f; O3[r] = 0.f;
        O4[r] = 0.f; O5[r] = 0.f; O6[r] = 0.f; O7[r] = 0.f;
    }
    float l_run = 0.f;

    short8 ahA0 = *(const short8*)(KPb);
    short8 ahA1 = *(const short8*)(KPb + 512);
    short8 ahB0, ahB1;

    for (int sp = 0; sp < 18; ++sp) {
        int m0 = sp * 64;                         // relative to mw (bases pre-offset)
        ahB0 = *(const short8*)(KPb + (size_t)(m0 + 32) * 32);
        ahB1 = *(const short8*)(KPb + (size_t)(m0 + 32) * 32 + 512);
        FSTEP(ahA0, ahA1, m0);
        int nm = (sp < 17) ? (m0 + 64) : 0;
        ahA0 = *(const short8*)(KPb + (size_t)nm * 32);
        ahA1 = *(const short8*)(KPb + (size_t)nm * 32 + 512);
        FSTEP(ahB0, ahB1, m0 + 32);
    }

    // ---- 2-wave combine: one barrier; each wave stores half the c-rows ----
    if (lane < 32) Lsh[wv][ln] = l_run;
    if (wv == 1) { OSHW(0, O0) OSHW(1, O1) OSHW(2, O2) OSHW(3, O3) }
    else         { OSHW(4, O4) OSHW(5, O5) OSHW(6, O6) OSHW(7, O7) }
    __syncthreads();
    size_t obase = (size_t)mq * ((size_t)CC * NN);
    if (wv == 0) {
        OSTORE(0, O0) OSTORE(1, O1) OSTORE(2, O2) OSTORE(3, O3)
        if (lane < 32) Lpart[mq * NN + n0 + ln] = Lsh[0][ln] + Lsh[1][ln];
    } else {
        OSTORE(4, O4) OSTORE(5, O5) OSTORE(6, O6) OSTORE(7, O7)
    }
}

// K4: fixed-max parts => single weight W[n] = gamma / sum_q L_q[n]. grid 36x256.
__global__ __launch_bounds__(256) void stats(
    const float* __restrict__ Lpart, const float* __restrict__ gamma,
    float* __restrict__ W)
{
    int n = blockIdx.x * 256 + threadIdx.x;
    float L = Lpart[n] + Lpart[NN + n] + Lpart[2 * NN + n] + Lpart[3 * NN + n];
    W[n] = gamma[0] / L;
}

// K5: out[c][n] = (sum_q Opart_q[c][n]) * W[n] + x[c][n]
__global__ __launch_bounds__(256) void combine(
    const unsigned short* __restrict__ Opart, const float* __restrict__ W,
    const float* __restrict__ x, float* __restrict__ out)
{
    int i = blockIdx.x * 256 + threadIdx.x;   // float4 index
    int flat = i * 4;
    int n = flat % NN;                        // 4-aligned, NN%4==0 so no row cross
    floatx4 acc = *(const floatx4*)&x[flat];
    floatx4 w = *(const floatx4*)&W[n];
    float s0 = 0.f, s1 = 0.f, s2 = 0.f, s3 = 0.f;
#pragma unroll
    for (int q = 0; q < 4; ++q) {
        ushortx4 o = *(const ushortx4*)(Opart + (size_t)q * ((size_t)CC * NN) + flat);
        s0 += bf2f(o[0]); s1 += bf2f(o[1]); s2 += bf2f(o[2]); s3 += bf2f(o[3]);
    }
    acc[0] += s0 * w[0]; acc[1] += s1 * w[1]; acc[2] += s2 * w[2]; acc[3] += s3 * w[3];
    *(floatx4*)&out[flat] = acc;
}

extern "C" void kernel_launch(void* const* d_in, const int* in_sizes, int n_in,
                              void* d_out, int out_size, void* d_ws, size_t ws_size,
                              hipStream_t stream) {
    const float* x  = (const float*)d_in[0];
    const float* xe = (const float*)d_in[1];
    const float* qw = (const float*)d_in[2];
    const float* qb = (const float*)d_in[3];
    const float* kw = (const float*)d_in[4];
    const float* kb = (const float*)d_in[5];
    const float* vw = (const float*)d_in[6];
    const float* vb = (const float*)d_in[7];
    const float* hp = (const float*)d_in[8];
    const float* wp = (const float*)d_in[9];
    const float* gm = (const float*)d_in[10];

    char* ws = (char*)d_ws;
    short* Qhi  = (short*)(ws + 0);                 // 589824 B
    short* Qlo  = (short*)(ws + 589824);            // 589824 B
    short* KP2  = (short*)(ws + 1179648);           // 589824 B
    short* WAhi = (short*)(ws + 1769472);           // 163840 B
    short* WAlo = (short*)(ws + 1933312);           // 163840 B
    short* VF   = (short*)(ws + 2097152);           // 4718592 B, ends 6815744
    unsigned short* Opart = (unsigned short*)(ws + 6815744);   // 18874368 B, ends 25690112
    // XB/EB staging overlays Opart (consumed by gemm_all before flash writes Opart)
    short* XBhi = (short*)(ws + 6815744);           // 4718592 B each
    short* XBlo = (short*)(ws + 11534336);
    short* EBhi = (short*)(ws + 16252928);
    short* EBlo = (short*)(ws + 20971520);
    float* Lpart = (float*)(ws + 25837568);         // 147456 B
    float* W     = (float*)(ws + 25985024);         // 36864 B used

    prep<<<dim3(1152, 2), dim3(256), 0, stream>>>(x, xe, XBhi, XBlo, EBhi, EBlo);
    wprep<<<dim3(40), dim3(256), 0, stream>>>(qw, kw, vw, WAhi, WAlo);
    gemm_all<<<dim3(144, 5), dim3(256), 0, stream>>>(
        XBhi, XBlo, EBhi, EBlo, WAhi, WAlo, qb, kb, hp, wp, vb, Qhi, Qlo, KP2, VF);
    flash<<<dim3(1152), dim3(128), 0, stream>>>(Qhi, Qlo, KP2, VF, Opart, Lpart);
    stats<<<dim3(36), dim3(256), 0, stream>>>(Lpart, gm, W);
    combine<<<dim3(2304), dim3(256), 0, stream>>>(Opart, W, x, (float*)d_out);
}

// Round 10
// 135.663 us; speedup vs baseline: 1.4221x; 1.0158x over previous
//
#include <hip/hip_runtime.h>
#include <hip/hip_bf16.h>

#define NN 9216
#define CC 256
#define LOG2E 1.4426950408889634f

typedef __attribute__((ext_vector_type(8))) short short8;
typedef __attribute__((ext_vector_type(16))) float floatx16;
typedef __attribute__((ext_vector_type(4))) float floatx4;
typedef __attribute__((ext_vector_type(4))) unsigned short ushortx4;

#if __has_builtin(__builtin_amdgcn_exp2f)
#define fexp2 __builtin_amdgcn_exp2f
#else
#define fexp2 exp2f
#endif

__device__ __forceinline__ unsigned short f2bf(float f) {
    unsigned u = __float_as_uint(f);
    u = u + 0x7fffu + ((u >> 16) & 1u);
    return (unsigned short)(u >> 16);
}
__device__ __forceinline__ float bf2f(unsigned short s) {
    return __uint_as_float(((unsigned)s) << 16);
}
__device__ __forceinline__ unsigned pack2bf(float a, float b) {
    union { __hip_bfloat162 h; unsigned u; } cv;
    cv.h = __float22bfloat162_rn(make_float2(a, b));
    return cv.u;
}
__device__ __forceinline__ floatx16 mfma_bf16(short8 a, short8 b, floatx16 c) {
    return __builtin_amdgcn_mfma_f32_32x32x16_bf16(a, b, c, 0, 0, 0);
}

// K0: transpose+hi/lo-split inputs into B-fragment order XB/EB[nt][kb][lane][8].
__global__ __launch_bounds__(256) void prep(
    const float* __restrict__ x, const float* __restrict__ xe,
    short* __restrict__ XBhi, short* __restrict__ XBlo,
    short* __restrict__ EBhi, short* __restrict__ EBlo)
{
    int t = threadIdx.x;
    const float* in = blockIdx.y ? xe : x;
    short* Dhi = blockIdx.y ? EBhi : XBhi;
    short* Dlo = blockIdx.y ? EBlo : XBlo;
    int tl = t & 31, sub = t >> 5;
    int nt = blockIdx.x >> 2, q4 = blockIdx.x & 3;
    int sub2 = q4 * 8 + sub;            // 0..31
    int kb_ = sub2 >> 1, hl = sub2 & 1;
    int n = nt * 32 + tl;
    int c0 = kb_ * 16 + hl * 8;
    union { unsigned short us[8]; short8 v8; } hi, lo;
#pragma unroll
    for (int j = 0; j < 8; ++j) {
        float val = in[(size_t)(c0 + j) * NN + n];
        unsigned short hb = f2bf(val);
        hi.us[j] = hb;
        lo.us[j] = f2bf(val - bf2f(hb));
    }
    size_t off = (((size_t)nt * 16 + kb_) * 64 + hl * 32 + tl) * 8;
    *(short8*)(Dhi + off) = hi.v8;
    *(short8*)(Dlo + off) = lo.v8;
}

// K0b: weights -> A-fragment order WA[ot][kb][lane][8], hi/lo split.
__global__ __launch_bounds__(256) void wprep(
    const float* __restrict__ qw, const float* __restrict__ kw,
    const float* __restrict__ vw,
    short* __restrict__ WAhi, short* __restrict__ WAlo)
{
    int g = blockIdx.x * 256 + threadIdx.x;     // 0..10239
    int lane = g & 63, kb_ = (g >> 6) & 15, ot = g >> 10;
    int o = lane & 31, half = lane >> 5;
    int c0 = kb_ * 16 + half * 8;
    const float* wsrc;
    int orow;
    float scale = 1.f;
    if (ot == 0) { wsrc = qw; orow = o; scale = LOG2E; }
    else if (ot == 1) { wsrc = kw; orow = o; }
    else { wsrc = vw; orow = (ot - 2) * 32 + o; }
    union { unsigned short us[8]; short8 v8; } hi, lo;
#pragma unroll
    for (int j = 0; j < 8; ++j) {
        float val = wsrc[(size_t)orow * 256 + c0 + j] * scale;
        unsigned short hb = f2bf(val);
        hi.us[j] = hb;
        lo.us[j] = f2bf(val - bf2f(hb));
    }
    size_t off = (((size_t)ot * 16 + kb_) * 64 + lane) * 8;
    *(short8*)(WAhi + off) = hi.v8;
    *(short8*)(WAlo + off) = lo.v8;
}

// K1: all projections via MFMA (see round-2 notes). grid (144, 5), 256 thr.
__global__ __launch_bounds__(256) void gemm_all(
    const short* __restrict__ XBhi, const short* __restrict__ XBlo,
    const short* __restrict__ EBhi, const short* __restrict__ EBlo,
    const short* __restrict__ WAhi, const short* __restrict__ WAlo,
    const float* __restrict__ qb, const float* __restrict__ kb,
    const float* __restrict__ hpos, const float* __restrict__ wpos,
    const float* __restrict__ vb,
    short* __restrict__ Qhi, short* __restrict__ Qlo,
    short* __restrict__ KP2, short* __restrict__ VF)
{
    __shared__ float lds[4][1024];
    int t = threadIdx.x;
    int wv = t >> 6, lane = t & 63, ln = lane & 31, h = lane >> 5;
    int nt = blockIdx.x * 2 + (wv & 1);
    int tile = blockIdx.y * 2 + (wv >> 1);

    const short* Bhi = (tile == 0 ? XBhi : EBhi) + (size_t)nt * 8192 + lane * 8;
    const short* Blo = (tile == 0 ? XBlo : EBlo) + (size_t)nt * 8192 + lane * 8;
    const short* Ahi = WAhi + (size_t)tile * 8192 + lane * 8;
    const short* Alo = WAlo + (size_t)tile * 8192 + lane * 8;

    floatx16 D;
#pragma unroll
    for (int r = 0; r < 16; ++r) D[r] = 0.f;
#pragma unroll
    for (int k = 0; k < 16; ++k) {
        short8 bh = *(const short8*)(Bhi + k * 512);
        short8 bl = *(const short8*)(Blo + k * 512);
        short8 ah = *(const short8*)(Ahi + k * 512);
        short8 al = *(const short8*)(Alo + k * 512);
        D = mfma_bf16(ah, bh, D);
        D = mfma_bf16(ah, bl, D);
        D = mfma_bf16(al, bh, D);
    }

    float* L = lds[wv];
#pragma unroll
    for (int r = 0; r < 16; ++r) {
        int row = (r & 3) + 8 * (r >> 2) + 4 * h;
        L[row * 32 + ((ln + row) & 31)] = D[r];     // (col+row)&31 bank swizzle
    }
    __syncthreads();

    if (tile == 0) {
        int n = nt * 32 + ln;
#pragma unroll
        for (int it = 0; it < 2; ++it) {
            int j0 = it * 16 + h * 8;
            union { unsigned short us[8]; short8 v8; } qh_, ql_;
#pragma unroll
            for (int jj = 0; jj < 8; ++jj) {
                int row = j0 + jj;
                float d = L[row * 32 + ((ln + row) & 31)] + qb[row] * LOG2E;
                unsigned short hb = f2bf(d);
                qh_.us[jj] = hb;
                ql_.us[jj] = f2bf(d - bf2f(hb));
            }
            *(short8*)(Qhi + (size_t)n * 32 + j0) = qh_.v8;
            *(short8*)(Qlo + (size_t)n * 32 + j0) = ql_.v8;
        }
    } else if (tile == 1) {
        int n = nt * 32 + ln;
        int hh = ((n >> 5) * 683) >> 11;     // n/96
        int ww = n - hh * 96;
#pragma unroll
        for (int it = 0; it < 2; ++it) {
            int jb0 = it * 16 + h * 8;
            union { unsigned short us[8]; short8 v8; } o;
#pragma unroll
            for (int jj = 0; jj < 8; ++jj) {
                int row = jb0 + jj;
                float d = L[row * 32 + ((ln + row) & 31)]
                        + kb[row] + hpos[row * 96 + hh] + wpos[row * 96 + ww];
                o.us[jj] = f2bf(d);
            }
            *(short8*)(KP2 + (size_t)nt * 1024 + it * 512 + h * 256 + ln * 8) = o.v8;
        }
    } else {
        int cc = tile - 2;
        float bias = vb[cc * 32 + ln];
#pragma unroll
        for (int it = 0; it < 2; ++it) {
            union { unsigned short us[8]; short8 v8; } o;
#pragma unroll
            for (int ee = 0; ee < 8; ++ee) {
                int ml = it * 16 + h * 8 + ee;
                float d = L[ln * 32 + ((ml + ln) & 31)];
                o.us[ee] = f2bf(d + bias);
            }
            *(short8*)(VF + ((size_t)(nt * 2 + it) * 8 + cc) * 512 + lane * 8) = o.v8;
        }
    }
}

// K3: flash attention (round-3 structure, proven: flash 88us) + V register prefetch.
// grid = 576 (144 nt-pairs x 4 m-quarters), 128 thr = 2 waves; wave = 32 n x 256 c,
// both waves stream the SAME m-quarter (identical V/KP addresses). Fixed-max
// softmax (max=0). NEW: the 16 V fragments of FSTEP s+1 are prefetched into a
// second named register set while FSTEP s computes (static double-buffer, unroll
// by 2 -> no runtime indexing, no scratch). Prefetch distance = 1 full FSTEP
// (QK + softmax + PV ~ 500+ cyc) >= L2 latency, hiding the V-load stall that
// dominated rounds 3-8. Pure dataflow change: no sync semantics, race-free.
#define PFV(VN, MOFF) do {                                                            \
    const short* Vp_ = Vb + (size_t)(MOFF) * 256;                                     \
    VN##0  = *(const short8*)(Vp_);                                                   \
    VN##1  = *(const short8*)(Vp_ + 512);                                             \
    VN##2  = *(const short8*)(Vp_ + 1024);                                            \
    VN##3  = *(const short8*)(Vp_ + 1536);                                            \
    VN##4  = *(const short8*)(Vp_ + 2048);                                            \
    VN##5  = *(const short8*)(Vp_ + 2560);                                            \
    VN##6  = *(const short8*)(Vp_ + 3072);                                            \
    VN##7  = *(const short8*)(Vp_ + 3584);                                            \
    VN##8  = *(const short8*)(Vp_ + 4096);                                            \
    VN##9  = *(const short8*)(Vp_ + 4608);                                            \
    VN##10 = *(const short8*)(Vp_ + 5120);                                            \
    VN##11 = *(const short8*)(Vp_ + 5632);                                            \
    VN##12 = *(const short8*)(Vp_ + 6144);                                            \
    VN##13 = *(const short8*)(Vp_ + 6656);                                            \
    VN##14 = *(const short8*)(Vp_ + 7168);                                            \
    VN##15 = *(const short8*)(Vp_ + 7680);                                            \
} while (0)

#define FSTEPP(AH0, AH1, VC, VN, MNEXT) do {                                          \
    PFV(VN, MNEXT);                                                                   \
    floatx16 S = {0.f,0.f,0.f,0.f,0.f,0.f,0.f,0.f,0.f,0.f,0.f,0.f,0.f,0.f,0.f,0.f};  \
    S = mfma_bf16(AH0, qf00, S);                                                      \
    S = mfma_bf16(AH0, qf01, S);                                                      \
    S = mfma_bf16(AH1, qf10, S);                                                      \
    S = mfma_bf16(AH1, qf11, S);                                                      \
    float ps = 0.f;                                                                   \
    _Pragma("unroll") for (int r = 0; r < 16; ++r) { S[r] = fexp2(S[r]); ps += S[r]; } \
    ps += __shfl_xor(ps, 32); l_run += ps;                                            \
    unsigned w0 = pack2bf(S[0], S[1]),  w1 = pack2bf(S[2], S[3]);                     \
    unsigned w2 = pack2bf(S[4], S[5]),  w3 = pack2bf(S[6], S[7]);                     \
    unsigned w4 = pack2bf(S[8], S[9]),  w5 = pack2bf(S[10], S[11]);                   \
    unsigned w6 = pack2bf(S[12], S[13]), w7 = pack2bf(S[14], S[15]);                  \
    {   unsigned p0 = h ? w0 : w2, p1 = h ? w1 : w3;                                  \
        unsigned e0 = (unsigned)__shfl_xor((int)p0, 32);                              \
        unsigned e1 = (unsigned)__shfl_xor((int)p1, 32);                              \
        union { unsigned u[4]; short8 v; } pf;                                        \
        pf.u[0] = h ? e0 : w0; pf.u[1] = h ? e1 : w1;                                 \
        pf.u[2] = h ? w2 : e0; pf.u[3] = h ? w3 : e1;                                 \
        O0 = mfma_bf16(VC##0, pf.v, O0); O1 = mfma_bf16(VC##1, pf.v, O1);             \
        O2 = mfma_bf16(VC##2, pf.v, O2); O3 = mfma_bf16(VC##3, pf.v, O3);             \
        O4 = mfma_bf16(VC##4, pf.v, O4); O5 = mfma_bf16(VC##5, pf.v, O5);             \
        O6 = mfma_bf16(VC##6, pf.v, O6); O7 = mfma_bf16(VC##7, pf.v, O7); }           \
    {   unsigned p0 = h ? w4 : w6, p1 = h ? w5 : w7;                                  \
        unsigned e0 = (unsigned)__shfl_xor((int)p0, 32);                              \
        unsigned e1 = (unsigned)__shfl_xor((int)p1, 32);                              \
        union { unsigned u[4]; short8 v; } pf;                                        \
        pf.u[0] = h ? e0 : w4; pf.u[1] = h ? e1 : w5;                                 \
        pf.u[2] = h ? w6 : e0; pf.u[3] = h ? w7 : e1;                                 \
        O0 = mfma_bf16(VC##8,  pf.v, O0); O1 = mfma_bf16(VC##9,  pf.v, O1);           \
        O2 = mfma_bf16(VC##10, pf.v, O2); O3 = mfma_bf16(VC##11, pf.v, O3);           \
        O4 = mfma_bf16(VC##12, pf.v, O4); O5 = mfma_bf16(VC##13, pf.v, O5);           \
        O6 = mfma_bf16(VC##14, pf.v, O6); O7 = mfma_bf16(VC##15, pf.v, O7); }         \
} while (0)

#define OGW(G, OG) { _Pragma("unroll") for (int r = 0; r < 16; ++r) { \
    int row = 32*(G) + (r & 3) + 8 * (r >> 2) + 4 * h;                \
    Opart[obase + (size_t)row * NN + n0 + ln] = f2bf(OG[r]); } }

__global__ __launch_bounds__(128) void flash(
    const short* __restrict__ Qhi, const short* __restrict__ Qlo,
    const short* __restrict__ KP2, const short* __restrict__ VT2,
    unsigned short* __restrict__ Opart, float* __restrict__ Lpart)
{
    int t = threadIdx.x;
    int wv = t >> 6;          // n-half within block
    int lane = t & 63;
    int ln = lane & 31;
    int h = lane >> 5;
    int nt = blockIdx.x >> 2, mq = blockIdx.x & 3;
    int n0 = nt * 64 + wv * 32;
    int mstart = mq * 2304;   // block-shared m-quarter

    int qoff = (n0 + ln) * 32 + h * 8;
    short8 qf00 = *(const short8*)(Qhi + qoff);
    short8 qf10 = *(const short8*)(Qhi + qoff + 16);
    short8 qf01 = *(const short8*)(Qlo + qoff);
    short8 qf11 = *(const short8*)(Qlo + qoff + 16);

    // Block-uniform V/KP bases: both waves issue identical addresses.
    const short* Vb  = VT2 + (size_t)mstart * 256 + (size_t)lane * 8;
    const short* KPb = KP2 + (size_t)mstart * 32 + (size_t)lane * 8;

    floatx16 O0, O1, O2, O3, O4, O5, O6, O7;
#pragma unroll
    for (int r = 0; r < 16; ++r) {
        O0[r] = 0.f; O1[r] = 0.f; O2[r] = 0.f; O3[r] = 0.f;
        O4[r] = 0.f; O5[r] = 0.f; O6[r] = 0.f; O7[r] = 0.f;
    }
    float l_run = 0.f;

    short8 vA0, vA1, vA2, vA3, vA4, vA5, vA6, vA7;
    short8 vA8, vA9, vA10, vA11, vA12, vA13, vA14, vA15;
    short8 vB0, vB1, vB2, vB3, vB4, vB5, vB6, vB7;
    short8 vB8, vB9, vB10, vB11, vB12, vB13, vB14, vB15;

    PFV(vA, 0);
    short8 ahA0 = *(const short8*)(KPb);
    short8 ahA1 = *(const short8*)(KPb + 512);
    short8 ahB0, ahB1;

    for (int sp = 0; sp < 36; ++sp) {
        int m0 = sp * 64;                         // relative to mstart (bases pre-offset)
        ahB0 = *(const short8*)(KPb + (size_t)(m0 + 32) * 32);
        ahB1 = *(const short8*)(KPb + (size_t)(m0 + 32) * 32 + 512);
        FSTEPP(ahA0, ahA1, vA, vB, m0 + 32);      // compute m0 with vA; prefetch vB
        int nm = (sp < 35) ? (m0 + 64) : 0;
        ahA0 = *(const short8*)(KPb + (size_t)nm * 32);
        ahA1 = *(const short8*)(KPb + (size_t)nm * 32 + 512);
        FSTEPP(ahB0, ahB1, vB, vA, nm);           // compute m0+32 with vB; prefetch vA
    }

    if (lane < 32) Lpart[mq * NN + n0 + ln] = l_run;
    size_t obase = (size_t)mq * ((size_t)CC * NN);
    OGW(0, O0) OGW(1, O1) OGW(2, O2) OGW(3, O3)
    OGW(4, O4) OGW(5, O5) OGW(6, O6) OGW(7, O7)
}

// K5: out[c][n] = (sum_q Opart_q[c][n]) * (gamma / sum_q L_q[n]) + x[c][n]
// (stats folded in: fixed-max parts => single weight per n)
__global__ __launch_bounds__(256) void combine(
    const unsigned short* __restrict__ Opart, const float* __restrict__ Lpart,
    const float* __restrict__ gamma, const float* __restrict__ x,
    float* __restrict__ out)
{
    int i = blockIdx.x * 256 + threadIdx.x;   // float4 index
    int flat = i * 4;
    int n = flat % NN;                        // 4-aligned, NN%4==0 so no row cross
    floatx4 acc = *(const floatx4*)&x[flat];
    floatx4 L0 = *(const floatx4*)&Lpart[n];
    floatx4 L1 = *(const floatx4*)&Lpart[NN + n];
    floatx4 L2 = *(const floatx4*)&Lpart[2 * NN + n];
    floatx4 L3 = *(const floatx4*)&Lpart[3 * NN + n];
    float g = gamma[0];
    float s0 = 0.f, s1 = 0.f, s2 = 0.f, s3 = 0.f;
#pragma unroll
    for (int q = 0; q < 4; ++q) {
        ushortx4 o = *(const ushortx4*)(Opart + (size_t)q * ((size_t)CC * NN) + flat);
        s0 += bf2f(o[0]); s1 += bf2f(o[1]); s2 += bf2f(o[2]); s3 += bf2f(o[3]);
    }
    acc[0] += s0 * (g / (L0[0] + L1[0] + L2[0] + L3[0]));
    acc[1] += s1 * (g / (L0[1] + L1[1] + L2[1] + L3[1]));
    acc[2] += s2 * (g / (L0[2] + L1[2] + L2[2] + L3[2]));
    acc[3] += s3 * (g / (L0[3] + L1[3] + L2[3] + L3[3]));
    *(floatx4*)&out[flat] = acc;
}

extern "C" void kernel_launch(void* const* d_in, const int* in_sizes, int n_in,
                              void* d_out, int out_size, void* d_ws, size_t ws_size,
                              hipStream_t stream) {
    const float* x  = (const float*)d_in[0];
    const float* xe = (const float*)d_in[1];
    const float* qw = (const float*)d_in[2];
    const float* qb = (const float*)d_in[3];
    const float* kw = (const float*)d_in[4];
    const float* kb = (const float*)d_in[5];
    const float* vw = (const float*)d_in[6];
    const float* vb = (const float*)d_in[7];
    const float* hp = (const float*)d_in[8];
    const float* wp = (const float*)d_in[9];
    const float* gm = (const float*)d_in[10];

    char* ws = (char*)d_ws;
    short* Qhi  = (short*)(ws + 0);                 // 589824 B
    short* Qlo  = (short*)(ws + 589824);            // 589824 B
    short* KP2  = (short*)(ws + 1179648);           // 589824 B
    short* WAhi = (short*)(ws + 1769472);           // 163840 B
    short* WAlo = (short*)(ws + 1933312);           // 163840 B
    short* VF   = (short*)(ws + 2097152);           // 4718592 B, ends 6815744
    unsigned short* Opart = (unsigned short*)(ws + 6815744);   // 18874368 B, ends 25690112
    // XB/EB staging overlays Opart (consumed by gemm_all before flash writes Opart)
    short* XBhi = (short*)(ws + 6815744);           // 4718592 B each
    short* XBlo = (short*)(ws + 11534336);
    short* EBhi = (short*)(ws + 16252928);
    short* EBlo = (short*)(ws + 20971520);
    float* Lpart = (float*)(ws + 25837568);         // 147456 B

    prep<<<dim3(1152, 2), dim3(256), 0, stream>>>(x, xe, XBhi, XBlo, EBhi, EBlo);
    wprep<<<dim3(40), dim3(256), 0, stream>>>(qw, kw, vw, WAhi, WAlo);
    gemm_all<<<dim3(144, 5), dim3(256), 0, stream>>>(
        XBhi, XBlo, EBhi, EBlo, WAhi, WAlo, qb, kb, hp, wp, vb, Qhi, Qlo, KP2, VF);
    flash<<<dim3(576), dim3(128), 0, stream>>>(Qhi, Qlo, KP2, VF, Opart, Lpart);
    combine<<<dim3(2304), dim3(256), 0, stream>>>(Opart, Lpart, gm, x, (float*)d_out);
}

// Round 11
// 114.132 us; speedup vs baseline: 1.6903x; 1.1886x over previous
//
#include <hip/hip_runtime.h>
#include <hip/hip_bf16.h>

#define NN 9216
#define CC 256
#define LOG2E 1.4426950408889634f

typedef __attribute__((ext_vector_type(8))) short short8;
typedef __attribute__((ext_vector_type(16))) float floatx16;
typedef __attribute__((ext_vector_type(4))) float floatx4;
typedef __attribute__((ext_vector_type(4))) unsigned short ushortx4;

#if __has_builtin(__builtin_amdgcn_exp2f)
#define fexp2 __builtin_amdgcn_exp2f
#else
#define fexp2 exp2f
#endif

__device__ __forceinline__ unsigned short f2bf(float f) {
    unsigned u = __float_as_uint(f);
    u = u + 0x7fffu + ((u >> 16) & 1u);
    return (unsigned short)(u >> 16);
}
__device__ __forceinline__ float bf2f(unsigned short s) {
    return __uint_as_float(((unsigned)s) << 16);
}
__device__ __forceinline__ unsigned pack2bf(float a, float b) {
    union { __hip_bfloat162 h; unsigned u; } cv;
    cv.h = __float22bfloat162_rn(make_float2(a, b));
    return cv.u;
}
__device__ __forceinline__ floatx16 mfma_bf16(short8 a, short8 b, floatx16 c) {
    return __builtin_amdgcn_mfma_f32_32x32x16_bf16(a, b, c, 0, 0, 0);
}

// K0: transpose+hi/lo-split inputs into B-fragment order XB/EB[nt][kb][lane][8].
__global__ __launch_bounds__(256) void prep(
    const float* __restrict__ x, const float* __restrict__ xe,
    short* __restrict__ XBhi, short* __restrict__ XBlo,
    short* __restrict__ EBhi, short* __restrict__ EBlo)
{
    int t = threadIdx.x;
    const float* in = blockIdx.y ? xe : x;
    short* Dhi = blockIdx.y ? EBhi : XBhi;
    short* Dlo = blockIdx.y ? EBlo : XBlo;
    int tl = t & 31, sub = t >> 5;
    int nt = blockIdx.x >> 2, q4 = blockIdx.x & 3;
    int sub2 = q4 * 8 + sub;            // 0..31
    int kb_ = sub2 >> 1, hl = sub2 & 1;
    int n = nt * 32 + tl;
    int c0 = kb_ * 16 + hl * 8;
    union { unsigned short us[8]; short8 v8; } hi, lo;
#pragma unroll
    for (int j = 0; j < 8; ++j) {
        float val = in[(size_t)(c0 + j) * NN + n];
        unsigned short hb = f2bf(val);
        hi.us[j] = hb;
        lo.us[j] = f2bf(val - bf2f(hb));
    }
    size_t off = (((size_t)nt * 16 + kb_) * 64 + hl * 32 + tl) * 8;
    *(short8*)(Dhi + off) = hi.v8;
    *(short8*)(Dlo + off) = lo.v8;
}

// K0b: weights -> A-fragment order WA[ot][kb][lane][8], hi/lo split.
__global__ __launch_bounds__(256) void wprep(
    const float* __restrict__ qw, const float* __restrict__ kw,
    const float* __restrict__ vw,
    short* __restrict__ WAhi, short* __restrict__ WAlo)
{
    int g = blockIdx.x * 256 + threadIdx.x;     // 0..10239
    int lane = g & 63, kb_ = (g >> 6) & 15, ot = g >> 10;
    int o = lane & 31, half = lane >> 5;
    int c0 = kb_ * 16 + half * 8;
    const float* wsrc;
    int orow;
    float scale = 1.f;
    if (ot == 0) { wsrc = qw; orow = o; scale = LOG2E; }
    else if (ot == 1) { wsrc = kw; orow = o; }
    else { wsrc = vw; orow = (ot - 2) * 32 + o; }
    union { unsigned short us[8]; short8 v8; } hi, lo;
#pragma unroll
    for (int j = 0; j < 8; ++j) {
        float val = wsrc[(size_t)orow * 256 + c0 + j] * scale;
        unsigned short hb = f2bf(val);
        hi.us[j] = hb;
        lo.us[j] = f2bf(val - bf2f(hb));
    }
    size_t off = (((size_t)ot * 16 + kb_) * 64 + lane) * 8;
    *(short8*)(WAhi + off) = hi.v8;
    *(short8*)(WAlo + off) = lo.v8;
}

// K1: all projections via MFMA (see round-2 notes). grid (144, 5), 256 thr.
__global__ __launch_bounds__(256) void gemm_all(
    const short* __restrict__ XBhi, const short* __restrict__ XBlo,
    const short* __restrict__ EBhi, const short* __restrict__ EBlo,
    const short* __restrict__ WAhi, const short* __restrict__ WAlo,
    const float* __restrict__ qb, const float* __restrict__ kb,
    const float* __restrict__ hpos, const float* __restrict__ wpos,
    const float* __restrict__ vb,
    short* __restrict__ Qhi, short* __restrict__ Qlo,
    short* __restrict__ KP2, short* __restrict__ VF)
{
    __shared__ float lds[4][1024];
    int t = threadIdx.x;
    int wv = t >> 6, lane = t & 63, ln = lane & 31, h = lane >> 5;
    int nt = blockIdx.x * 2 + (wv & 1);
    int tile = blockIdx.y * 2 + (wv >> 1);

    const short* Bhi = (tile == 0 ? XBhi : EBhi) + (size_t)nt * 8192 + lane * 8;
    const short* Blo = (tile == 0 ? XBlo : EBlo) + (size_t)nt * 8192 + lane * 8;
    const short* Ahi = WAhi + (size_t)tile * 8192 + lane * 8;
    const short* Alo = WAlo + (size_t)tile * 8192 + lane * 8;

    floatx16 D;
#pragma unroll
    for (int r = 0; r < 16; ++r) D[r] = 0.f;
#pragma unroll
    for (int k = 0; k < 16; ++k) {
        short8 bh = *(const short8*)(Bhi + k * 512);
        short8 bl = *(const short8*)(Blo + k * 512);
        short8 ah = *(const short8*)(Ahi + k * 512);
        short8 al = *(const short8*)(Alo + k * 512);
        D = mfma_bf16(ah, bh, D);
        D = mfma_bf16(ah, bl, D);
        D = mfma_bf16(al, bh, D);
    }

    float* L = lds[wv];
#pragma unroll
    for (int r = 0; r < 16; ++r) {
        int row = (r & 3) + 8 * (r >> 2) + 4 * h;
        L[row * 32 + ((ln + row) & 31)] = D[r];     // (col+row)&31 bank swizzle
    }
    __syncthreads();

    if (tile == 0) {
        int n = nt * 32 + ln;
#pragma unroll
        for (int it = 0; it < 2; ++it) {
            int j0 = it * 16 + h * 8;
            union { unsigned short us[8]; short8 v8; } qh_, ql_;
#pragma unroll
            for (int jj = 0; jj < 8; ++jj) {
                int row = j0 + jj;
                float d = L[row * 32 + ((ln + row) & 31)] + qb[row] * LOG2E;
                unsigned short hb = f2bf(d);
                qh_.us[jj] = hb;
                ql_.us[jj] = f2bf(d - bf2f(hb));
            }
            *(short8*)(Qhi + (size_t)n * 32 + j0) = qh_.v8;
            *(short8*)(Qlo + (size_t)n * 32 + j0) = ql_.v8;
        }
    } else if (tile == 1) {
        int n = nt * 32 + ln;
        int hh = ((n >> 5) * 683) >> 11;     // n/96
        int ww = n - hh * 96;
#pragma unroll
        for (int it = 0; it < 2; ++it) {
            int jb0 = it * 16 + h * 8;
            union { unsigned short us[8]; short8 v8; } o;
#pragma unroll
            for (int jj = 0; jj < 8; ++jj) {
                int row = jb0 + jj;
                float d = L[row * 32 + ((ln + row) & 31)]
                        + kb[row] + hpos[row * 96 + hh] + wpos[row * 96 + ww];
                o.us[jj] = f2bf(d);
            }
            *(short8*)(KP2 + (size_t)nt * 1024 + it * 512 + h * 256 + ln * 8) = o.v8;
        }
    } else {
        int cc = tile - 2;
        float bias = vb[cc * 32 + ln];
#pragma unroll
        for (int it = 0; it < 2; ++it) {
            union { unsigned short us[8]; short8 v8; } o;
#pragma unroll
            for (int ee = 0; ee < 8; ++ee) {
                int ml = it * 16 + h * 8 + ee;
                float d = L[ln * 32 + ((ml + ln) & 31)];
                o.us[ee] = f2bf(d + bias);
            }
            *(short8*)(VF + ((size_t)(nt * 2 + it) * 8 + cc) * 512 + lane * 8) = o.v8;
        }
    }
}

// K3: flash attention — exact round-3 dataflow (measured flash 88us), with the
// m-part count made a RUNTIME parameter. grid = 144 nt-pairs x nparts; 128 thr =
// 2 waves; wave = 32 n x 256 c over mlen m; both waves stream the SAME m-part
// (identical V/KP addresses). nparts=8 doubles resident waves (9/CU offered vs
// 4.5) at identical total FLOPs and per-wave registers — attacks the measured
// grid-starvation (R3: only 4.5 waves/CU offered, 3 resident, ~1900cy/FSTEP of
// exposed latency). Fixed-max softmax (max=0): energies ~N(0,~10) in log2
// domain, far from f32 range limits, so exp2(S) direct is exact softmax.
#define FSTEP(AH0, AH1, M0) do {                                                      \
    const size_t mo_ = (size_t)(M0) * 256;                                            \
    short8 va0 = *(const short8*)(Vb + mo_);                                          \
    short8 va1 = *(const short8*)(Vb + mo_ + 512);                                    \
    short8 va2 = *(const short8*)(Vb + mo_ + 1024);                                   \
    short8 va3 = *(const short8*)(Vb + mo_ + 1536);                                   \
    floatx16 S = {0.f,0.f,0.f,0.f,0.f,0.f,0.f,0.f,0.f,0.f,0.f,0.f,0.f,0.f,0.f,0.f};  \
    S = mfma_bf16(AH0, qf00, S);                                                      \
    S = mfma_bf16(AH0, qf01, S);                                                      \
    S = mfma_bf16(AH1, qf10, S);                                                      \
    S = mfma_bf16(AH1, qf11, S);                                                      \
    short8 va4 = *(const short8*)(Vb + mo_ + 2048);                                   \
    short8 va5 = *(const short8*)(Vb + mo_ + 2560);                                   \
    short8 va6 = *(const short8*)(Vb + mo_ + 3072);                                   \
    short8 va7 = *(const short8*)(Vb + mo_ + 3584);                                   \
    float ps = 0.f;                                                                   \
    _Pragma("unroll") for (int r = 0; r < 16; ++r) { S[r] = fexp2(S[r]); ps += S[r]; } \
    ps += __shfl_xor(ps, 32); l_run += ps;                                            \
    unsigned w0 = pack2bf(S[0], S[1]),  w1 = pack2bf(S[2], S[3]);                     \
    unsigned w2 = pack2bf(S[4], S[5]),  w3 = pack2bf(S[6], S[7]);                     \
    unsigned w4 = pack2bf(S[8], S[9]),  w5 = pack2bf(S[10], S[11]);                   \
    unsigned w6 = pack2bf(S[12], S[13]), w7 = pack2bf(S[14], S[15]);                  \
    {   unsigned p0 = h ? w0 : w2, p1 = h ? w1 : w3;                                  \
        unsigned e0 = (unsigned)__shfl_xor((int)p0, 32);                              \
        unsigned e1 = (unsigned)__shfl_xor((int)p1, 32);                              \
        union { unsigned u[4]; short8 v; } pf;                                        \
        pf.u[0] = h ? e0 : w0; pf.u[1] = h ? e1 : w1;                                 \
        pf.u[2] = h ? w2 : e0; pf.u[3] = h ? w3 : e1;                                 \
        O0 = mfma_bf16(va0, pf.v, O0); O1 = mfma_bf16(va1, pf.v, O1);                 \
        O2 = mfma_bf16(va2, pf.v, O2); O3 = mfma_bf16(va3, pf.v, O3);                 \
        O4 = mfma_bf16(va4, pf.v, O4); O5 = mfma_bf16(va5, pf.v, O5);                 \
        O6 = mfma_bf16(va6, pf.v, O6); O7 = mfma_bf16(va7, pf.v, O7); }               \
    short8 vb0 = *(const short8*)(Vb + mo_ + 4096);                                   \
    short8 vb1 = *(const short8*)(Vb + mo_ + 4608);                                   \
    short8 vb2 = *(const short8*)(Vb + mo_ + 5120);                                   \
    short8 vb3 = *(const short8*)(Vb + mo_ + 5632);                                   \
    short8 vb4 = *(const short8*)(Vb + mo_ + 6144);                                   \
    short8 vb5 = *(const short8*)(Vb + mo_ + 6656);                                   \
    short8 vb6 = *(const short8*)(Vb + mo_ + 7168);                                   \
    short8 vb7 = *(const short8*)(Vb + mo_ + 7680);                                   \
    {   unsigned p0 = h ? w4 : w6, p1 = h ? w5 : w7;                                  \
        unsigned e0 = (unsigned)__shfl_xor((int)p0, 32);                              \
        unsigned e1 = (unsigned)__shfl_xor((int)p1, 32);                              \
        union { unsigned u[4]; short8 v; } pf;                                        \
        pf.u[0] = h ? e0 : w4; pf.u[1] = h ? e1 : w5;                                 \
        pf.u[2] = h ? w6 : e0; pf.u[3] = h ? w7 : e1;                                 \
        O0 = mfma_bf16(vb0, pf.v, O0); O1 = mfma_bf16(vb1, pf.v, O1);                 \
        O2 = mfma_bf16(vb2, pf.v, O2); O3 = mfma_bf16(vb3, pf.v, O3);                 \
        O4 = mfma_bf16(vb4, pf.v, O4); O5 = mfma_bf16(vb5, pf.v, O5);                 \
        O6 = mfma_bf16(vb6, pf.v, O6); O7 = mfma_bf16(vb7, pf.v, O7); }               \
} while (0)

#define OGW(G, OG) { _Pragma("unroll") for (int r = 0; r < 16; ++r) { \
    int row = 32*(G) + (r & 3) + 8 * (r >> 2) + 4 * h;                \
    Opart[obase + (size_t)row * NN + n0 + ln] = f2bf(OG[r]); } }

__global__ __launch_bounds__(128, 2) void flash(
    const short* __restrict__ Qhi, const short* __restrict__ Qlo,
    const short* __restrict__ KP2, const short* __restrict__ VT2,
    unsigned short* __restrict__ Opart, float* __restrict__ Lpart,
    int mqmask, int mshift, int mlen)
{
    int t = threadIdx.x;
    int wv = t >> 6;          // n-half within block
    int lane = t & 63;
    int ln = lane & 31;
    int h = lane >> 5;
    int nt = blockIdx.x >> mshift, mq = blockIdx.x & mqmask;
    int n0 = nt * 64 + wv * 32;
    int mstart = mq * mlen;   // block-shared m-part

    int qoff = (n0 + ln) * 32 + h * 8;
    short8 qf00 = *(const short8*)(Qhi + qoff);
    short8 qf10 = *(const short8*)(Qhi + qoff + 16);
    short8 qf01 = *(const short8*)(Qlo + qoff);
    short8 qf11 = *(const short8*)(Qlo + qoff + 16);

    // Block-uniform V/KP bases: both waves issue identical addresses.
    const short* Vb  = VT2 + (size_t)mstart * 256 + (size_t)lane * 8;
    const short* KPb = KP2 + (size_t)mstart * 32 + (size_t)lane * 8;

    floatx16 O0, O1, O2, O3, O4, O5, O6, O7;
#pragma unroll
    for (int r = 0; r < 16; ++r) {
        O0[r] = 0.f; O1[r] = 0.f; O2[r] = 0.f; O3[r] = 0.f;
        O4[r] = 0.f; O5[r] = 0.f; O6[r] = 0.f; O7[r] = 0.f;
    }
    float l_run = 0.f;

    short8 ahA0 = *(const short8*)(KPb);
    short8 ahA1 = *(const short8*)(KPb + 512);
    short8 ahB0, ahB1;

    int nsp = mlen >> 6;      // iterations of 2 FSTEPs (64 m per iteration)
    for (int sp = 0; sp < nsp; ++sp) {
        int m0 = sp * 64;                         // relative to mstart (bases pre-offset)
        ahB0 = *(const short8*)(KPb + (size_t)(m0 + 32) * 32);
        ahB1 = *(const short8*)(KPb + (size_t)(m0 + 32) * 32 + 512);
        FSTEP(ahA0, ahA1, m0);
        int nm = (sp < nsp - 1) ? (m0 + 64) : 0;
        ahA0 = *(const short8*)(KPb + (size_t)nm * 32);
        ahA1 = *(const short8*)(KPb + (size_t)nm * 32 + 512);
        FSTEP(ahB0, ahB1, m0 + 32);
    }

    if (lane < 32) Lpart[mq * NN + n0 + ln] = l_run;
    size_t obase = (size_t)mq * ((size_t)CC * NN);
    OGW(0, O0) OGW(1, O1) OGW(2, O2) OGW(3, O3)
    OGW(4, O4) OGW(5, O5) OGW(6, O6) OGW(7, O7)
}

// K5: out[c][n] = (sum_q Opart_q[c][n]) * (gamma / sum_q L_q[n]) + x[c][n]
// (stats folded in: fixed-max parts => single weight per n; nparts runtime)
__global__ __launch_bounds__(256) void combine(
    const unsigned short* __restrict__ Opart, const float* __restrict__ Lpart,
    const float* __restrict__ gamma, const float* __restrict__ x,
    float* __restrict__ out, int nparts)
{
    int i = blockIdx.x * 256 + threadIdx.x;   // float4 index
    int flat = i * 4;
    int n = flat % NN;                        // 4-aligned, NN%4==0 so no row cross
    floatx4 acc = *(const floatx4*)&x[flat];
    float Ls0 = 0.f, Ls1 = 0.f, Ls2 = 0.f, Ls3 = 0.f;
    float s0 = 0.f, s1 = 0.f, s2 = 0.f, s3 = 0.f;
    for (int q = 0; q < nparts; ++q) {
        floatx4 Lq = *(const floatx4*)&Lpart[q * NN + n];
        Ls0 += Lq[0]; Ls1 += Lq[1]; Ls2 += Lq[2]; Ls3 += Lq[3];
        ushortx4 o = *(const ushortx4*)(Opart + (size_t)q * ((size_t)CC * NN) + flat);
        s0 += bf2f(o[0]); s1 += bf2f(o[1]); s2 += bf2f(o[2]); s3 += bf2f(o[3]);
    }
    float g = gamma[0];
    acc[0] += s0 * (g / Ls0);
    acc[1] += s1 * (g / Ls1);
    acc[2] += s2 * (g / Ls2);
    acc[3] += s3 * (g / Ls3);
    *(floatx4*)&out[flat] = acc;
}

extern "C" void kernel_launch(void* const* d_in, const int* in_sizes, int n_in,
                              void* d_out, int out_size, void* d_ws, size_t ws_size,
                              hipStream_t stream) {
    const float* x  = (const float*)d_in[0];
    const float* xe = (const float*)d_in[1];
    const float* qw = (const float*)d_in[2];
    const float* qb = (const float*)d_in[3];
    const float* kw = (const float*)d_in[4];
    const float* kb = (const float*)d_in[5];
    const float* vw = (const float*)d_in[6];
    const float* vb = (const float*)d_in[7];
    const float* hp = (const float*)d_in[8];
    const float* wp = (const float*)d_in[9];
    const float* gm = (const float*)d_in[10];

    char* ws = (char*)d_ws;
    short* Qhi  = (short*)(ws + 0);                 // 589824 B
    short* Qlo  = (short*)(ws + 589824);            // 589824 B
    short* KP2  = (short*)(ws + 1179648);           // 589824 B
    short* WAhi = (short*)(ws + 1769472);           // 163840 B
    short* WAlo = (short*)(ws + 1933312);           // 163840 B
    short* VF   = (short*)(ws + 2097152);           // 4718592 B, ends 6815744

    const size_t OPART_OFF = 6815744;
    const size_t PART_BYTES = (size_t)CC * NN * 2;  // 4718592 per part
    // pick 8 m-parts (2x the wave count at identical FLOPs) if workspace allows
    int nparts = 4, mshift = 2;
    size_t need8 = OPART_OFF + 8 * PART_BYTES + (size_t)8 * NN * 4;  // ~44.9 MB
    if (ws_size >= need8) { nparts = 8; mshift = 3; }
    unsigned short* Opart = (unsigned short*)(ws + OPART_OFF);
    float* Lpart = (float*)(ws + OPART_OFF + (size_t)nparts * PART_BYTES);

    // XB/EB staging overlays Opart (consumed by gemm_all before flash writes it)
    short* XBhi = (short*)(ws + OPART_OFF);
    short* XBlo = (short*)(ws + OPART_OFF + 4718592);
    short* EBhi = (short*)(ws + OPART_OFF + 2 * 4718592);
    short* EBlo = (short*)(ws + OPART_OFF + 3 * 4718592);

    prep<<<dim3(1152, 2), dim3(256), 0, stream>>>(x, xe, XBhi, XBlo, EBhi, EBlo);
    wprep<<<dim3(40), dim3(256), 0, stream>>>(qw, kw, vw, WAhi, WAlo);
    gemm_all<<<dim3(144, 5), dim3(256), 0, stream>>>(
        XBhi, XBlo, EBhi, EBlo, WAhi, WAlo, qb, kb, hp, wp, vb, Qhi, Qlo, KP2, VF);
    flash<<<dim3(144 * nparts), dim3(128), 0, stream>>>(
        Qhi, Qlo, KP2, VF, Opart, Lpart, nparts - 1, mshift, NN / nparts);
    combine<<<dim3(2304), dim3(256), 0, stream>>>(Opart, Lpart, gm, x, (float*)d_out, nparts);
}